// Round 16
// baseline (323.604 us; speedup 1.0000x reference)
//
#include <hip/hip_runtime.h>
#include <hip/hip_bf16.h>
#include <stdint.h>

#define NN 4096
#define MAXNZ 1536   // cap on nnz per row of a2 (bank-padded, x8); /8 = 192 dchunks

// CSR entry format: (val << 20) | (col << 2).  Rows are emitted bank-grouped:
// contiguous segments per bank (col%32), each segment padded to x8 with
// val=0 entries (col = bank id) so a4row's 8-elems-per-lane consumption is
// bank-aligned (per-instruction bank multiplicity ~1-2 -> conflict-free).

// ---------------------------------------------------------------------------
// K1: scan_k — one pass over adj per row, 4x unrolled (4 independent wave
// loads in flight per iteration). Produces nbr, deg, bit-adjacency abits,
// degree feats. Lane ln keeps ballot word ln.
// ---------------------------------------------------------------------------
__global__ __launch_bounds__(256) void scan_k(const float* __restrict__ adj,
                                              int* __restrict__ nbr,
                                              int* __restrict__ deg,
                                              unsigned long long* __restrict__ abits,
                                              float* __restrict__ feats) {
    __shared__ int nlist[4][64];
    int tid = threadIdx.x;
    int wv = tid >> 6, ln = tid & 63;
    int v = blockIdx.x * 4 + wv;
    size_t rb = (size_t)v * NN;
    int total = 0;
    unsigned long long w0 = 0;
    for (int base = 0; base < NN; base += 256) {
        float v0 = adj[rb + base + ln];
        float v1 = adj[rb + base + 64 + ln];
        float v2 = adj[rb + base + 128 + ln];
        float v3 = adj[rb + base + 192 + ln];
        int q4 = (base >> 8) << 2;   // word index of sub-block 0
        {
            unsigned long long m = __ballot(v0 > 0.5f);
            if (v0 > 0.5f) {
                int pos = total + __popcll(m & ((1ull << ln) - 1ull));
                if (pos < 64) nlist[wv][pos] = base + ln;
            }
            if (ln == q4 + 0) w0 = m;
            total += __popcll(m);
        }
        {
            unsigned long long m = __ballot(v1 > 0.5f);
            if (v1 > 0.5f) {
                int pos = total + __popcll(m & ((1ull << ln) - 1ull));
                if (pos < 64) nlist[wv][pos] = base + 64 + ln;
            }
            if (ln == q4 + 1) w0 = m;
            total += __popcll(m);
        }
        {
            unsigned long long m = __ballot(v2 > 0.5f);
            if (v2 > 0.5f) {
                int pos = total + __popcll(m & ((1ull << ln) - 1ull));
                if (pos < 64) nlist[wv][pos] = base + 128 + ln;
            }
            if (ln == q4 + 2) w0 = m;
            total += __popcll(m);
        }
        {
            unsigned long long m = __ballot(v3 > 0.5f);
            if (v3 > 0.5f) {
                int pos = total + __popcll(m & ((1ull << ln) - 1ull));
                if (pos < 64) nlist[wv][pos] = base + 192 + ln;
            }
            if (ln == q4 + 3) w0 = m;
            total += __popcll(m);
        }
    }
    abits[(size_t)v * 64 + ln] = w0;
    int degL = min(total, 64);
    if (ln < degL) nbr[v * 64 + ln] = nlist[wv][ln];
    if (ln == 0) {
        deg[v] = total;
        float degf = (float)total;
        feats[v * 16 + 12] = degf;
        feats[v * 16 + 13] = degf * degf;
        feats[v * 16 + 14] = degf;           // diag(A^2) = deg (symmetric 0/1)
    }
}

// ---------------------------------------------------------------------------
// K2: cra2_k — role-split merged dispatch:
//   blocks [0, 4096):    a2 = adj@adj -> BANK-GROUPED packed CSR
//   blocks [4096, 5120): cr_feat from the L2-resident bitmask (4 nodes/block)
// Bank prefix is computed with __shfl_up entirely inside wave 0 — NO
// barriers in divergent code (round-15 bug: divergent __syncthreads()).
// ---------------------------------------------------------------------------
__global__ __launch_bounds__(256) void cra2_k(const unsigned long long* __restrict__ abits,
                                              const int* __restrict__ nbr,
                                              const int* __restrict__ deg,
                                              unsigned int* __restrict__ csr,
                                              int* __restrict__ cnt,
                                              float* __restrict__ feats) {
    __shared__ __align__(16) unsigned int smem[NN + 512];
    int tid = threadIdx.x;
    int bid = blockIdx.x;
    int wv = tid >> 6, ln = tid & 63;

    if (bid < NN) {
        // ------------------- a2 role -------------------
        unsigned int* acc   = smem;                     // [4096] counts
        int* us             = (int*)(smem + NN);        // [64]
        int* dus            = (int*)(smem + NN + 64);   // [64]
        unsigned int* lcnt  = smem + NN + 128;          // [256] per-thread nz
        unsigned int* bbase = smem + NN + 384;          // [33] bank bases
        unsigned int* bcnt  = smem + NN + 420;          // [32] actual bank nz
        int v = bid;
        for (int j = tid; j < NN; j += 256) acc[j] = 0u;
        int dv = min(deg[v], 64);
        if (tid < dv) {
            int u = nbr[v * 64 + tid];
            us[tid] = u;
            dus[tid] = min(deg[u], 64);
        }
        __syncthreads();
        for (int p = tid; p < dv * 64; p += 256) {
            int i = p >> 6, wi = p & 63;
            int u = us[i];
            if (wi < dus[i]) atomicAdd(&acc[nbr[u * 64 + wi]], 1u);
        }
        __syncthreads();
        // thread tid's 16 cols (tid+256m) all lie in bank tid%32
        unsigned int local = 0;
        #pragma unroll
        for (int m = 0; m < 16; m++) local += (acc[tid + 256 * m] != 0u);
        lcnt[tid] = local;
        __syncthreads();
        // wave 0, lanes 0..31: bank sizes + shfl exclusive prefix (no barriers)
        if (tid < 32) {
            unsigned int cb = 0;
            #pragma unroll
            for (int j = 0; j < 8; j++) cb += lcnt[tid + 32 * j];
            bcnt[tid] = cb;
            unsigned int padded = (cb + 7u) & ~7u;
            unsigned int scan = padded;                 // inclusive scan
            #pragma unroll
            for (int off = 1; off < 32; off <<= 1) {
                unsigned int n = (unsigned int)__shfl_up((int)scan, off, 64);
                if (tid >= off) scan += n;
            }
            bbase[tid] = scan - padded;                 // exclusive
            if (tid == 31) bbase[32] = scan;            // padded total
        }
        __syncthreads();
        int b = tid & 31;
        // within-bank offset: sum of lcnt of same-bank threads before me
        unsigned int off = 0;
        {
            int myrank = tid >> 5;
            #pragma unroll
            for (int j = 0; j < 8; j++) {
                unsigned int lc = lcnt[b + 32 * j];
                if (j < myrank) off += lc;
            }
        }
        unsigned int pos = bbase[b] + off;
        unsigned int* dst = csr + (size_t)v * MAXNZ;
        #pragma unroll
        for (int m = 0; m < 16; m++) {
            unsigned int a = acc[tid + 256 * m];
            if (a) {
                if (pos < 1520u) dst[pos] = (a << 20) | ((unsigned int)(tid + 256 * m) << 2);
                pos++;
            }
        }
        // pads: bank b's tail [bbase[b]+bcnt[b], bbase[b+1]) -> val=0, col=b
        if (tid < 32) {
            unsigned int p0 = bbase[tid] + bcnt[tid], p1 = bbase[tid + 1];
            for (unsigned int p = p0; p < p1; p++)
                if (p < 1520u) dst[p] = ((unsigned int)tid) << 2;
        }
        if (tid == 0) cnt[v] = (int)min(bbase[32], 1520u);
    } else {
        // ------------------- cr role -------------------
        unsigned long long* rows = (unsigned long long*)smem;   // [4][64], 2 KB
        int* mems = (int*)(smem + 1024);                        // [4][64], 1 KB
        int v = (bid - NN) * 4 + wv;

        int dv = deg[v];
        int degL = min(dv, 64);
        int c = min(dv + 1, 64);

        int nl = (ln < degL) ? nbr[v * 64 + ln] : 0;
        int isless = (ln < degL && nl < v) ? 1 : 0;
        int pos = isless;
        #pragma unroll
        for (int off = 32; off; off >>= 1) pos += __shfl_xor(pos, off, 64);

        int mem = 0;
        if (ln < c) {
            if (ln < pos)       mem = nl;
            else if (ln == pos) mem = v;
            else                mem = nbr[v * 64 + ln - 1];
        }
        mems[wv * 64 + ln] = mem;
        __syncthreads();

        unsigned long long mask = 0ull;
        {
            const unsigned long long* rowb = abits + (size_t)mem * 64;
            for (int j = 0; j < c; j++) {
                int mj = mems[wv * 64 + j];
                unsigned long long w = rowb[mj >> 6];
                mask |= ((w >> (mj & 63)) & 1ull) << j;
            }
        }
        if (ln >= c) mask = 0ull;
        rows[wv * 64 + ln] = mask;
        __syncthreads();

        int tpart = 0;
        float epart = 0.f, wpart = 0.f;
        if (ln < c) {
            unsigned long long mm = mask;
            while (mm) {
                int j = __ffsll(mm) - 1;
                mm &= mm - 1;
                tpart += __popcll(mask & rows[wv * 64 + j]);
            }
            if (ln != pos) {
                int cn = __popcll(rows[wv * 64 + pos] & mask);
                float D = (float)cn + 1.0f;
                epart = D;
                wpart = D * (D - 1.0f) * 0.5f;
            }
        }
        float es = epart, wsum2 = wpart;
        int ts = tpart;
        #pragma unroll
        for (int off = 32; off; off >>= 1) {
            es += __shfl_xor(es, off, 64);
            wsum2 += __shfl_xor(wsum2, off, 64);
            ts += __shfl_xor(ts, off, 64);
        }

        if (ln == 0) {
            float degf = (float)dv;
            float k = degf + 1.0f;
            float E = 0.5f * (es + degf);
            float W = wsum2 + degf * (degf - 1.0f) * 0.5f;
            float T = (float)ts / 6.0f;
            float f3 = T;
            float f2 = W - 3.0f * T;
            float f1 = E * (k - 2.0f) - 2.0f * f2 - 3.0f * f3;
            float tot = k * (k - 1.0f) * (k - 2.0f) / 6.0f;
            float f0 = tot - f1 - f2 - f3;
            if (k < 3.0f) { f0 = f1 = f2 = f3 = 0.f; }
            float s = f0 + f1 + f2 + f3 + 1e-10f;
            feats[v * 16 + 0] = f0 / s;
            feats[v * 16 + 1] = f1 / s;
            feats[v * 16 + 2] = f2 / s;
            feats[v * 16 + 3] = f3 / s;
        }
    }
}

// ---------------------------------------------------------------------------
// K3: fused sparse a4-row + top-8 + embedding — round-10 structure on
// bank-grouped rows. Double-chunk passes (one 8-run per lane = one bank),
// 4-way entry fusion, shfl-only top-8.
// ---------------------------------------------------------------------------
__device__ __forceinline__ void do4(unsigned int* acc, uint4 E, unsigned int W) {
    atomicAdd(&acc[(E.x >> 2) & 0xFFFu], W * (E.x >> 20));
    atomicAdd(&acc[(E.y >> 2) & 0xFFFu], W * (E.y >> 20));
    atomicAdd(&acc[(E.z >> 2) & 0xFFFu], W * (E.z >> 20));
    atomicAdd(&acc[(E.w >> 2) & 0xFFFu], W * (E.w >> 20));
}

__global__ __launch_bounds__(512) void a4row_k(const unsigned int* __restrict__ csr,
                                               const int* __restrict__ cnt,
                                               const float* __restrict__ feats,
                                               const float* __restrict__ e_w,
                                               const float* __restrict__ e_b,
                                               float* __restrict__ x0) {
    __shared__ unsigned int acc[NN];                       // 16 KB
    __shared__ __align__(16) unsigned int rowe[MAXNZ];     // 6 KB
    __shared__ unsigned int wtops[64];
    int tid = threadIdx.x;
    int wv = tid >> 6, ln = tid & 63;
    int v = blockIdx.x;

    for (int j = tid; j < NN; j += 512) acc[j] = 0u;

    int nv = cnt[v];                 // already a multiple of 8
    const unsigned int* rowv = csr + (size_t)v * MAXNZ;
    for (int i = tid; i < nv; i += 512) {
        unsigned int e = rowv[i];
        unsigned int u = (e >> 2) & 0xFFFu;
        unsigned int w = e >> 20;
        unsigned int nc = w ? ((unsigned int)cnt[u] >> 3) : 0u;  // dchunks
        rowe[i] = u | (w << 12) | (nc << 19);
    }
    __syncthreads();

    const uint4* csr4 = (const uint4*)csr;
    for (int i0 = wv * 4; i0 < nv; i0 += 32) {
        uint4 q = *(const uint4*)&rowe[i0];
        int c1 = (int)(q.x >> 19);
        int c2 = c1 + (int)(q.y >> 19);
        int c3 = c2 + (int)(q.z >> 19);
        int tot = c3 + (int)(q.w >> 19);
        unsigned int s0 = ((q.x & 0xFFFu) * 192u + 1024u)                    | (((q.x >> 12) & 0x7Fu) << 21);
        unsigned int s1 = ((q.y & 0xFFFu) * 192u + 1024u - (unsigned int)c1) | (((q.y >> 12) & 0x7Fu) << 21);
        unsigned int s2 = ((q.z & 0xFFFu) * 192u + 1024u - (unsigned int)c2) | (((q.z >> 12) & 0x7Fu) << 21);
        unsigned int s3 = ((q.w & 0xFFFu) * 192u + 1024u - (unsigned int)c3) | (((q.w >> 12) & 0x7Fu) << 21);
        for (int g = ln; g < tot; g += 64) {
            unsigned int sel = (g < c1) ? s0 : ((g < c2) ? s1 : ((g < c3) ? s2 : s3));
            unsigned int d2 = ((sel & 0x1FFFFFu) + (unsigned int)g - 1024u) << 1;
            const uint4* p = csr4 + d2;
            uint4 E0 = p[0];
            uint4 E1 = p[1];
            unsigned int W = sel >> 21;
            do4(acc, E0, W);
            do4(acc, E1, W);
        }
    }
    __syncthreads();

    // per-thread top-8 over 8 conflict-free LDS reads
    unsigned int best[8];
    #pragma unroll
    for (int q = 0; q < 8; q++) best[q] = 0u;
    #pragma unroll
    for (int m = 0; m < 8; m++) {
        unsigned int val = acc[tid + 512 * m];
        if (val > best[7]) {
            best[7] = val;
            #pragma unroll
            for (int s = 7; s > 0; s--) {
                if (best[s] > best[s - 1]) {
                    unsigned int t2 = best[s - 1]; best[s - 1] = best[s]; best[s] = t2;
                } else break;
            }
        }
    }

    // per-wave extract of 8 maxima (shfl-only)
    unsigned int wave_val = 0u;
    #pragma unroll
    for (int r = 0; r < 8; r++) {
        unsigned int m = best[0];
        #pragma unroll
        for (int off = 32; off; off >>= 1)
            m = max(m, (unsigned int)__shfl_xor((int)m, off, 64));
        unsigned long long bb = __ballot(best[0] == m);
        int src = __ffsll(bb) - 1;
        if (ln == src) {
            #pragma unroll
            for (int s = 0; s < 7; s++) best[s] = best[s + 1];
            best[7] = 0u;
        }
        if (ln == r) wave_val = m;
    }
    if (ln < 8) wtops[wv * 8 + ln] = wave_val;
    __syncthreads();

    // wave 0: merge 64 candidates, then fused embedding
    if (wv == 0) {
        unsigned int cand = wtops[ln];
        unsigned int myv = 0u;
        #pragma unroll
        for (int r = 0; r < 8; r++) {
            unsigned int m = cand;
            #pragma unroll
            for (int off = 32; off; off >>= 1)
                m = max(m, (unsigned int)__shfl_xor((int)m, off, 64));
            unsigned long long bb = __ballot(cand == m);
            int src = __ffsll(bb) - 1;
            if (ln == src) cand = 0u;
            if (ln == r) myv = m;
        }
        int d = ln;
        float s = e_b[d];
        s += feats[v * 16 + 0]  * e_w[0 * 64 + d];
        s += feats[v * 16 + 1]  * e_w[1 * 64 + d];
        s += feats[v * 16 + 2]  * e_w[2 * 64 + d];
        s += feats[v * 16 + 3]  * e_w[3 * 64 + d];
        #pragma unroll
        for (int j = 0; j < 8; j++) {
            float mj = (float)(unsigned int)__shfl((int)myv, j, 64);
            s += mj * e_w[(4 + j) * 64 + d];
        }
        s += feats[v * 16 + 12] * e_w[12 * 64 + d];
        s += feats[v * 16 + 13] * e_w[13 * 64 + d];
        s += feats[v * 16 + 14] * e_w[14 * 64 + d];
        x0[(size_t)v * 64 + d] = s;
    }
}

// ---------------------------------------------------------------------------
// K4: one GNN layer. For li==2, accumulate block column sums directly into
// out[64] via fp32 atomics (out pre-zeroed by hipMemsetAsync).
// ---------------------------------------------------------------------------
__global__ __launch_bounds__(256) void layer_k(const float* __restrict__ xin,
                                               float* __restrict__ xout,
                                               const float* __restrict__ w1,
                                               const float* __restrict__ b1,
                                               const float* __restrict__ w2,
                                               const float* __restrict__ b2,
                                               const float* __restrict__ eps,
                                               const int* __restrict__ nbr,
                                               const int* __restrict__ deg,
                                               float* __restrict__ out,
                                               int li) {
    __shared__ float h[4][64], t[4][64];
    int tid = threadIdx.x;
    int wv = tid >> 6, d = tid & 63;
    int v = blockIdx.x * 4 + wv;
    float xv = xin[(size_t)v * 64 + d];
    int dv = min(deg[v], 64);
    const int* nl = nbr + v * 64;
    float agg = 0.f;
    int j = 0;
    for (; j + 4 <= dv; j += 4) {
        int n0 = nl[j], n1 = nl[j + 1], n2 = nl[j + 2], n3 = nl[j + 3];
        float a0 = xin[(size_t)n0 * 64 + d];
        float a1 = xin[(size_t)n1 * 64 + d];
        float a2v = xin[(size_t)n2 * 64 + d];
        float a3 = xin[(size_t)n3 * 64 + d];
        agg += (a0 + a1) + (a2v + a3);
    }
    for (; j < dv; j++) agg += xin[(size_t)nl[j] * 64 + d];
    float hv = (1.0f + eps[li]) * xv + agg;
    h[wv][d] = hv;
    __syncthreads();
    float s = b1[li * 64 + d];
    #pragma unroll 8
    for (int k = 0; k < 64; k++) s += h[wv][k] * w1[li * 4096 + k * 64 + d];
    s = fmaxf(s, 0.f);
    t[wv][d] = s;
    __syncthreads();
    float o = b2[li * 64 + d];
    #pragma unroll 8
    for (int k = 0; k < 64; k++) o += t[wv][k] * w2[li * 4096 + k * 64 + d];
    if (li == 2) {
        h[wv][d] = o;
        __syncthreads();
        if (wv == 0)
            atomicAdd(&out[d], (h[0][d] + h[1][d]) + (h[2][d] + h[3][d]));
    } else {
        xout[(size_t)v * 64 + d] = o;
    }
}

// ---------------------------------------------------------------------------
extern "C" void kernel_launch(void* const* d_in, const int* in_sizes, int n_in,
                              void* d_out, int out_size, void* d_ws, size_t ws_size,
                              hipStream_t stream) {
    const float* adj = (const float*)d_in[0];
    const float* e_w = (const float*)d_in[1];
    const float* e_b = (const float*)d_in[2];
    const float* w1  = (const float*)d_in[3];
    const float* b1  = (const float*)d_in[4];
    const float* w2  = (const float*)d_in[5];
    const float* b2  = (const float*)d_in[6];
    const float* eps = (const float*)d_in[7];
    float* out = (float*)d_out;

    char* ws = (char*)d_ws;
    unsigned int*       csr     = (unsigned int*)(ws);                  // 24 MB
    int*                nbr     = (int*)(ws + 25165824);                // 1 MB
    int*                deg     = (int*)(ws + 26214400);                // 16 KB
    int*                cnt     = (int*)(ws + 26230784);                // 16 KB
    float*              feats   = (float*)(ws + 26247168);              // 256 KB
    float*              x0      = (float*)(ws + 26509312);              // 1 MB
    float*              x1      = (float*)(ws + 27557888);              // 1 MB
    unsigned long long* abits   = (unsigned long long*)(ws + 28868608); // 2 MB

    hipMemsetAsync(out, 0, 64 * sizeof(float), stream);
    scan_k<<<1024, 256, 0, stream>>>(adj, nbr, deg, abits, feats);
    cra2_k<<<5120, 256, 0, stream>>>(abits, nbr, deg, csr, cnt, feats);
    a4row_k<<<4096, 512, 0, stream>>>(csr, cnt, feats, e_w, e_b, x0);
    layer_k<<<1024, 256, 0, stream>>>(x0, x1, w1, b1, w2, b2, eps, nbr, deg, out, 0);
    layer_k<<<1024, 256, 0, stream>>>(x1, x0, w1, b1, w2, b2, eps, nbr, deg, out, 1);
    layer_k<<<1024, 256, 0, stream>>>(x0, x1, w1, b1, w2, b2, eps, nbr, deg, out, 2);
}

// Round 17
// 291.019 us; speedup vs baseline: 1.1120x; 1.1120x over previous
//
#include <hip/hip_runtime.h>
#include <hip/hip_bf16.h>
#include <stdint.h>

#define NN 4096
#define MAXNZ 1536   // entries per CSR row (16-bit each => 3 KB stride)

// CSR entry format (16-bit): (val << 12) | col.  val <= 15; a2 values > 15
// (the diagonal, = deg) are SPLIT into multiple same-col entries (linearity).
// Row stride 3072 B; consumption per 8 elems = one uint4 (16 B) load.

// ---------------------------------------------------------------------------
// K1: scan_k — one pass over adj per row, 4x unrolled. Produces nbr, deg,
// bit-adjacency abits (2 MB), degree feats. Lane ln keeps ballot word ln.
// ---------------------------------------------------------------------------
__global__ __launch_bounds__(256) void scan_k(const float* __restrict__ adj,
                                              int* __restrict__ nbr,
                                              int* __restrict__ deg,
                                              unsigned long long* __restrict__ abits,
                                              float* __restrict__ feats) {
    __shared__ int nlist[4][64];
    int tid = threadIdx.x;
    int wv = tid >> 6, ln = tid & 63;
    int v = blockIdx.x * 4 + wv;
    size_t rb = (size_t)v * NN;
    int total = 0;
    unsigned long long w0 = 0;
    for (int base = 0; base < NN; base += 256) {
        float v0 = adj[rb + base + ln];
        float v1 = adj[rb + base + 64 + ln];
        float v2 = adj[rb + base + 128 + ln];
        float v3 = adj[rb + base + 192 + ln];
        int q4 = (base >> 8) << 2;
        {
            unsigned long long m = __ballot(v0 > 0.5f);
            if (v0 > 0.5f) {
                int pos = total + __popcll(m & ((1ull << ln) - 1ull));
                if (pos < 64) nlist[wv][pos] = base + ln;
            }
            if (ln == q4 + 0) w0 = m;
            total += __popcll(m);
        }
        {
            unsigned long long m = __ballot(v1 > 0.5f);
            if (v1 > 0.5f) {
                int pos = total + __popcll(m & ((1ull << ln) - 1ull));
                if (pos < 64) nlist[wv][pos] = base + 64 + ln;
            }
            if (ln == q4 + 1) w0 = m;
            total += __popcll(m);
        }
        {
            unsigned long long m = __ballot(v2 > 0.5f);
            if (v2 > 0.5f) {
                int pos = total + __popcll(m & ((1ull << ln) - 1ull));
                if (pos < 64) nlist[wv][pos] = base + 128 + ln;
            }
            if (ln == q4 + 2) w0 = m;
            total += __popcll(m);
        }
        {
            unsigned long long m = __ballot(v3 > 0.5f);
            if (v3 > 0.5f) {
                int pos = total + __popcll(m & ((1ull << ln) - 1ull));
                if (pos < 64) nlist[wv][pos] = base + 192 + ln;
            }
            if (ln == q4 + 3) w0 = m;
            total += __popcll(m);
        }
    }
    abits[(size_t)v * 64 + ln] = w0;
    int degL = min(total, 64);
    if (ln < degL) nbr[v * 64 + ln] = nlist[wv][ln];
    if (ln == 0) {
        deg[v] = total;
        float degf = (float)total;
        feats[v * 16 + 12] = degf;
        feats[v * 16 + 13] = degf * degf;
        feats[v * 16 + 14] = degf;           // diag(A^2) = deg (symmetric 0/1)
    }
}

// ---------------------------------------------------------------------------
// K2: cra2_k — role-split merged dispatch:
//   blocks [0, 4096):    a2 = adj@adj -> 16-bit packed CSR (values > 15
//                        split across entries), stride-256 extraction,
//                        rows padded to x8 (val=0, distinct cols)
//   blocks [4096, 5120): cr_feat from the L2-resident bitmask (4 nodes/block)
// ---------------------------------------------------------------------------
__global__ __launch_bounds__(256) void cra2_k(const unsigned long long* __restrict__ abits,
                                              const int* __restrict__ nbr,
                                              const int* __restrict__ deg,
                                              unsigned int* __restrict__ csr,
                                              int* __restrict__ cnt,
                                              float* __restrict__ feats) {
    __shared__ __align__(16) unsigned int smem[NN + 132];
    int tid = threadIdx.x;
    int bid = blockIdx.x;
    int wv = tid >> 6, ln = tid & 63;

    if (bid < NN) {
        // ------------------- a2 role -------------------
        unsigned int* acc = smem;
        int* us  = (int*)(smem + NN + 1);
        int* dus = (int*)(smem + NN + 66);
        int v = bid;
        for (int j = tid; j < NN; j += 256) acc[j] = 0u;
        if (tid == 0) smem[NN] = 0u;
        int dv = min(deg[v], 64);
        if (tid < dv) {
            int u = nbr[v * 64 + tid];
            us[tid] = u;
            dus[tid] = min(deg[u], 64);
        }
        __syncthreads();
        for (int p = tid; p < dv * 64; p += 256) {
            int i = p >> 6, wi = p & 63;
            int u = us[i];
            if (wi < dus[i]) atomicAdd(&acc[nbr[u * 64 + wi]], 1u);
        }
        __syncthreads();
        unsigned int local = 0;
        #pragma unroll
        for (int m = 0; m < 16; m++) {
            unsigned int a = acc[tid + 256 * m];
            local += (a + 14u) / 15u;            // #entries after splitting
        }
        unsigned int pos = atomicAdd(&smem[NN], local);
        unsigned short* dst = (unsigned short*)((char*)csr + (size_t)v * 3072);
        #pragma unroll
        for (int m = 0; m < 16; m++) {
            unsigned int a = acc[tid + 256 * m];
            unsigned int col = (unsigned int)(tid + 256 * m);
            while (a) {
                unsigned int w = a > 15u ? 15u : a;
                if (pos < 1520u) dst[pos] = (unsigned short)((w << 12) | col);
                pos++;
                a -= w;
            }
        }
        __syncthreads();
        unsigned int bs = min(smem[NN], 1520u);
        unsigned int padto = (bs + 7u) & ~7u;
        if (tid < padto - bs) dst[bs + tid] = (unsigned short)(bs + tid);  // val=0
        if (tid == 0) cnt[v] = (int)bs;
    } else {
        // ------------------- cr role -------------------
        unsigned long long* rows = (unsigned long long*)smem;   // [4][64], 2 KB
        int* mems = (int*)(smem + 1024);                        // [4][64], 1 KB
        int v = (bid - NN) * 4 + wv;

        int dv = deg[v];
        int degL = min(dv, 64);
        int c = min(dv + 1, 64);

        int nl = (ln < degL) ? nbr[v * 64 + ln] : 0;
        int isless = (ln < degL && nl < v) ? 1 : 0;
        int pos = isless;
        #pragma unroll
        for (int off = 32; off; off >>= 1) pos += __shfl_xor(pos, off, 64);

        int mem = 0;
        if (ln < c) {
            if (ln < pos)       mem = nl;
            else if (ln == pos) mem = v;
            else                mem = nbr[v * 64 + ln - 1];
        }
        mems[wv * 64 + ln] = mem;
        __syncthreads();

        unsigned long long mask = 0ull;
        {
            const unsigned long long* rowb = abits + (size_t)mem * 64;
            for (int j = 0; j < c; j++) {
                int mj = mems[wv * 64 + j];
                unsigned long long w = rowb[mj >> 6];
                mask |= ((w >> (mj & 63)) & 1ull) << j;
            }
        }
        if (ln >= c) mask = 0ull;
        rows[wv * 64 + ln] = mask;
        __syncthreads();

        int tpart = 0;
        float epart = 0.f, wpart = 0.f;
        if (ln < c) {
            unsigned long long mm = mask;
            while (mm) {
                int j = __ffsll(mm) - 1;
                mm &= mm - 1;
                tpart += __popcll(mask & rows[wv * 64 + j]);
            }
            if (ln != pos) {
                int cn = __popcll(rows[wv * 64 + pos] & mask);
                float D = (float)cn + 1.0f;
                epart = D;
                wpart = D * (D - 1.0f) * 0.5f;
            }
        }
        float es = epart, wsum2 = wpart;
        int ts = tpart;
        #pragma unroll
        for (int off = 32; off; off >>= 1) {
            es += __shfl_xor(es, off, 64);
            wsum2 += __shfl_xor(wsum2, off, 64);
            ts += __shfl_xor(ts, off, 64);
        }

        if (ln == 0) {
            float degf = (float)dv;
            float k = degf + 1.0f;
            float E = 0.5f * (es + degf);
            float W = wsum2 + degf * (degf - 1.0f) * 0.5f;
            float T = (float)ts / 6.0f;
            float f3 = T;
            float f2 = W - 3.0f * T;
            float f1 = E * (k - 2.0f) - 2.0f * f2 - 3.0f * f3;
            float tot = k * (k - 1.0f) * (k - 2.0f) / 6.0f;
            float f0 = tot - f1 - f2 - f3;
            if (k < 3.0f) { f0 = f1 = f2 = f3 = 0.f; }
            float s = f0 + f1 + f2 + f3 + 1e-10f;
            feats[v * 16 + 0] = f0 / s;
            feats[v * 16 + 1] = f1 / s;
            feats[v * 16 + 2] = f2 / s;
            feats[v * 16 + 3] = f3 / s;
        }
    }
}

// ---------------------------------------------------------------------------
// K3: fused sparse a4-row + top-8 + embedding — round-14 structure on
// 16-bit CSR: each 8-element lane-pass = ONE uint4 load (halved CSR bytes).
// 4-way entry fusion with pre-biased packed selects; shfl-only top-8.
// ---------------------------------------------------------------------------
__device__ __forceinline__ void do8(unsigned int* acc, uint4 E, unsigned int W) {
    atomicAdd(&acc[E.x & 0xFFFu],         W * ((E.x >> 12) & 0xFu));
    atomicAdd(&acc[(E.x >> 16) & 0xFFFu], W * (E.x >> 28));
    atomicAdd(&acc[E.y & 0xFFFu],         W * ((E.y >> 12) & 0xFu));
    atomicAdd(&acc[(E.y >> 16) & 0xFFFu], W * (E.y >> 28));
    atomicAdd(&acc[E.z & 0xFFFu],         W * ((E.z >> 12) & 0xFu));
    atomicAdd(&acc[(E.z >> 16) & 0xFFFu], W * (E.z >> 28));
    atomicAdd(&acc[E.w & 0xFFFu],         W * ((E.w >> 12) & 0xFu));
    atomicAdd(&acc[(E.w >> 16) & 0xFFFu], W * (E.w >> 28));
}

__global__ __launch_bounds__(512) void a4row_k(const unsigned int* __restrict__ csr,
                                               const int* __restrict__ cnt,
                                               const float* __restrict__ feats,
                                               const float* __restrict__ e_w,
                                               const float* __restrict__ e_b,
                                               float* __restrict__ x0) {
    __shared__ unsigned int acc[NN];                       // 16 KB
    __shared__ __align__(16) unsigned int rowe[MAXNZ];     // 6 KB
    __shared__ unsigned int wtops[64];
    int tid = threadIdx.x;
    int wv = tid >> 6, ln = tid & 63;
    int v = blockIdx.x;

    for (int j = tid; j < NN; j += 512) acc[j] = 0u;

    int nv = cnt[v];
    int nvp = (nv + 7) & ~7;
    const unsigned short* rowv = (const unsigned short*)((const char*)csr + (size_t)v * 3072);
    for (int i = tid; i < nvp; i += 512) {
        unsigned int e = rowv[i];
        unsigned int u = e & 0xFFFu;
        unsigned int w = e >> 12;                            // <= 15
        unsigned int nc = w ? (((unsigned int)cnt[u] + 7u) >> 3) : 0u; // dchunks <= 192
        rowe[i] = u | (w << 12) | (nc << 16);
    }
    __syncthreads();

    const uint4* csr4 = (const uint4*)csr;   // row u starts at uint4 index u*192
    for (int i0 = wv * 4; i0 < nvp; i0 += 32) {
        uint4 q = *(const uint4*)&rowe[i0];
        int c1 = (int)(q.x >> 16);
        int c2 = c1 + (int)(q.y >> 16);
        int c3 = c2 + (int)(q.z >> 16);
        int tot = c3 + (int)(q.w >> 16);
        unsigned int s0 = ((q.x & 0xFFFu) * 192u + 1024u)                    | (((q.x >> 12) & 0xFu) << 21);
        unsigned int s1 = ((q.y & 0xFFFu) * 192u + 1024u - (unsigned int)c1) | (((q.y >> 12) & 0xFu) << 21);
        unsigned int s2 = ((q.z & 0xFFFu) * 192u + 1024u - (unsigned int)c2) | (((q.z >> 12) & 0xFu) << 21);
        unsigned int s3 = ((q.w & 0xFFFu) * 192u + 1024u - (unsigned int)c3) | (((q.w >> 12) & 0xFu) << 21);
        for (int g = ln; g < tot; g += 64) {
            unsigned int sel = (g < c1) ? s0 : ((g < c2) ? s1 : ((g < c3) ? s2 : s3));
            unsigned int idx = (sel & 0x1FFFFFu) + (unsigned int)g - 1024u;
            uint4 E = csr4[idx];
            do8(acc, E, sel >> 21);
        }
    }
    __syncthreads();

    // per-thread top-8 over 8 conflict-free LDS reads
    unsigned int best[8];
    #pragma unroll
    for (int q = 0; q < 8; q++) best[q] = 0u;
    #pragma unroll
    for (int m = 0; m < 8; m++) {
        unsigned int val = acc[tid + 512 * m];
        if (val > best[7]) {
            best[7] = val;
            #pragma unroll
            for (int s = 7; s > 0; s--) {
                if (best[s] > best[s - 1]) {
                    unsigned int t2 = best[s - 1]; best[s - 1] = best[s]; best[s] = t2;
                } else break;
            }
        }
    }

    // per-wave extract of 8 maxima (shfl-only)
    unsigned int wave_val = 0u;
    #pragma unroll
    for (int r = 0; r < 8; r++) {
        unsigned int m = best[0];
        #pragma unroll
        for (int off = 32; off; off >>= 1)
            m = max(m, (unsigned int)__shfl_xor((int)m, off, 64));
        unsigned long long bb = __ballot(best[0] == m);
        int src = __ffsll(bb) - 1;
        if (ln == src) {
            #pragma unroll
            for (int s = 0; s < 7; s++) best[s] = best[s + 1];
            best[7] = 0u;
        }
        if (ln == r) wave_val = m;
    }
    if (ln < 8) wtops[wv * 8 + ln] = wave_val;
    __syncthreads();

    // wave 0: merge 64 candidates, then fused embedding
    if (wv == 0) {
        unsigned int cand = wtops[ln];
        unsigned int myv = 0u;
        #pragma unroll
        for (int r = 0; r < 8; r++) {
            unsigned int m = cand;
            #pragma unroll
            for (int off = 32; off; off >>= 1)
                m = max(m, (unsigned int)__shfl_xor((int)m, off, 64));
            unsigned long long bb = __ballot(cand == m);
            int src = __ffsll(bb) - 1;
            if (ln == src) cand = 0u;
            if (ln == r) myv = m;
        }
        int d = ln;
        float s = e_b[d];
        s += feats[v * 16 + 0]  * e_w[0 * 64 + d];
        s += feats[v * 16 + 1]  * e_w[1 * 64 + d];
        s += feats[v * 16 + 2]  * e_w[2 * 64 + d];
        s += feats[v * 16 + 3]  * e_w[3 * 64 + d];
        #pragma unroll
        for (int j = 0; j < 8; j++) {
            float mj = (float)(unsigned int)__shfl((int)myv, j, 64);
            s += mj * e_w[(4 + j) * 64 + d];
        }
        s += feats[v * 16 + 12] * e_w[12 * 64 + d];
        s += feats[v * 16 + 13] * e_w[13 * 64 + d];
        s += feats[v * 16 + 14] * e_w[14 * 64 + d];
        x0[(size_t)v * 64 + d] = s;
    }
}

// ---------------------------------------------------------------------------
// K4: one GNN layer. For li==2, accumulate block column sums directly into
// out[64] via fp32 atomics (out pre-zeroed by hipMemsetAsync).
// ---------------------------------------------------------------------------
__global__ __launch_bounds__(256) void layer_k(const float* __restrict__ xin,
                                               float* __restrict__ xout,
                                               const float* __restrict__ w1,
                                               const float* __restrict__ b1,
                                               const float* __restrict__ w2,
                                               const float* __restrict__ b2,
                                               const float* __restrict__ eps,
                                               const int* __restrict__ nbr,
                                               const int* __restrict__ deg,
                                               float* __restrict__ out,
                                               int li) {
    __shared__ float h[4][64], t[4][64];
    int tid = threadIdx.x;
    int wv = tid >> 6, d = tid & 63;
    int v = blockIdx.x * 4 + wv;
    float xv = xin[(size_t)v * 64 + d];
    int dv = min(deg[v], 64);
    const int* nl = nbr + v * 64;
    float agg = 0.f;
    int j = 0;
    for (; j + 4 <= dv; j += 4) {
        int n0 = nl[j], n1 = nl[j + 1], n2 = nl[j + 2], n3 = nl[j + 3];
        float a0 = xin[(size_t)n0 * 64 + d];
        float a1 = xin[(size_t)n1 * 64 + d];
        float a2v = xin[(size_t)n2 * 64 + d];
        float a3 = xin[(size_t)n3 * 64 + d];
        agg += (a0 + a1) + (a2v + a3);
    }
    for (; j < dv; j++) agg += xin[(size_t)nl[j] * 64 + d];
    float hv = (1.0f + eps[li]) * xv + agg;
    h[wv][d] = hv;
    __syncthreads();
    float s = b1[li * 64 + d];
    #pragma unroll 8
    for (int k = 0; k < 64; k++) s += h[wv][k] * w1[li * 4096 + k * 64 + d];
    s = fmaxf(s, 0.f);
    t[wv][d] = s;
    __syncthreads();
    float o = b2[li * 64 + d];
    #pragma unroll 8
    for (int k = 0; k < 64; k++) o += t[wv][k] * w2[li * 4096 + k * 64 + d];
    if (li == 2) {
        h[wv][d] = o;
        __syncthreads();
        if (wv == 0)
            atomicAdd(&out[d], (h[0][d] + h[1][d]) + (h[2][d] + h[3][d]));
    } else {
        xout[(size_t)v * 64 + d] = o;
    }
}

// ---------------------------------------------------------------------------
extern "C" void kernel_launch(void* const* d_in, const int* in_sizes, int n_in,
                              void* d_out, int out_size, void* d_ws, size_t ws_size,
                              hipStream_t stream) {
    const float* adj = (const float*)d_in[0];
    const float* e_w = (const float*)d_in[1];
    const float* e_b = (const float*)d_in[2];
    const float* w1  = (const float*)d_in[3];
    const float* b1  = (const float*)d_in[4];
    const float* w2  = (const float*)d_in[5];
    const float* b2  = (const float*)d_in[6];
    const float* eps = (const float*)d_in[7];
    float* out = (float*)d_out;

    char* ws = (char*)d_ws;
    unsigned int*       csr     = (unsigned int*)(ws);                  // 12 MB (16-bit entries)
    int*                nbr     = (int*)(ws + 25165824);                // 1 MB
    int*                deg     = (int*)(ws + 26214400);                // 16 KB
    int*                cnt     = (int*)(ws + 26230784);                // 16 KB
    float*              feats   = (float*)(ws + 26247168);              // 256 KB
    float*              x0      = (float*)(ws + 26509312);              // 1 MB
    float*              x1      = (float*)(ws + 27557888);              // 1 MB
    unsigned long long* abits   = (unsigned long long*)(ws + 28868608); // 2 MB

    hipMemsetAsync(out, 0, 64 * sizeof(float), stream);
    scan_k<<<1024, 256, 0, stream>>>(adj, nbr, deg, abits, feats);
    cra2_k<<<5120, 256, 0, stream>>>(abits, nbr, deg, csr, cnt, feats);
    a4row_k<<<4096, 512, 0, stream>>>(csr, cnt, feats, e_w, e_b, x0);
    layer_k<<<1024, 256, 0, stream>>>(x0, x1, w1, b1, w2, b2, eps, nbr, deg, out, 0);
    layer_k<<<1024, 256, 0, stream>>>(x1, x0, w1, b1, w2, b2, eps, nbr, deg, out, 1);
    layer_k<<<1024, 256, 0, stream>>>(x0, x1, w1, b1, w2, b2, eps, nbr, deg, out, 2);
}